// Round 3
// baseline (9143.578 us; speedup 1.0000x reference)
//
#include <hip/hip_runtime.h>
#include <cstdint>
#include <cstddef>

#define NBLK 128
#define NT   256
#define ROWS 64
#define DD   100
#define HH   110
#define NS   63
#define SLOTSZ (NBLK * 256)          // floats per parity

typedef __bf16 bf16x8 __attribute__((ext_vector_type(8)));
typedef float  f32x16 __attribute__((ext_vector_type(16)));

struct Params {
  const float* W; const float* yini; const float* zini;
  const float* g0; const float* b0; const float* g1; const float* b1;
  const float* g2; const float* b2; const float* g3; const float* b3;
  const float* w0; const float* w1; const float* w2;
  float* out; float* slots; int* flags;
};

__device__ __forceinline__ float agent_ld(const float* p_) {
  return __hip_atomic_load(p_, __ATOMIC_RELAXED, __HIP_MEMORY_SCOPE_AGENT);
}
__device__ __forceinline__ void agent_st(float* p_, float v) {
  __hip_atomic_store(p_, v, __ATOMIC_RELAXED, __HIP_MEMORY_SCOPE_AGENT);
}

// arrive: all partial stores acked at MALL (vmcnt 0 per wave), then one flag store.
__device__ __forceinline__ void arrive(int* flags, int g) {
  asm volatile("s_waitcnt vmcnt(0)" ::: "memory");
  __syncthreads();
  if (threadIdx.x == 0)
    __hip_atomic_store(&flags[blockIdx.x * 16], g, __ATOMIC_RELAXED,
                       __HIP_MEMORY_SCOPE_AGENT);
}
// wait: thread t polls block t's flag; read-only, no RMW contention.
__device__ __forceinline__ void wait_all(int* flags, int g) {
  if (threadIdx.x < NBLK) {
    while (__hip_atomic_load(&flags[threadIdx.x * 16], __ATOMIC_RELAXED,
                             __HIP_MEMORY_SCOPE_AGENT) < g)
      __builtin_amdgcn_s_sleep(1);
  }
  __syncthreads();
  asm volatile("" ::: "memory");
}

// flat combine: thread tid sums entry tid over all 128 block slots (coalesced).
__device__ __forceinline__ float combine_read(const float* slp, int tid) {
  float a0 = 0.f, a1 = 0.f, a2 = 0.f, a3 = 0.f;
  const float* q = slp + tid;
#pragma unroll
  for (int b = 0; b < NBLK; b += 4) {
    a0 += agent_ld(q + (b + 0) * 256);
    a1 += agent_ld(q + (b + 1) * 256);
    a2 += agent_ld(q + (b + 2) * 256);
    a3 += agent_ld(q + (b + 3) * 256);
  }
  return (a0 + a1) + (a2 + a3);
}

// issue B-fragment global loads (w[k][n], masked to zero outside K x N)
template<int K, int N>
__device__ __forceinline__ void issueB(const float* wg, int n, int half, float (*t)[8]) {
#pragma unroll
  for (int c = 0; c < 7; ++c) {
#pragma unroll
    for (int j = 0; j < 8; ++j) {
      int k = c * 16 + half * 8 + j;
      t[c][j] = (k < K && n < N) ? wg[k * N + n] : 0.f;
    }
  }
}

// two 32-row tiles (M=64) sharing the B fragments
__device__ __forceinline__ void run_mfma2(const __bf16* hs, const float (*t)[8],
                                          int col, int half, f32x16* acc) {
  acc[0] = (f32x16)(0.f);
  acc[1] = (f32x16)(0.f);
#pragma unroll
  for (int c = 0; c < 7; ++c) {
    bf16x8 bfv;
#pragma unroll
    for (int j = 0; j < 8; ++j) bfv[j] = (__bf16)t[c][j];
    bf16x8 a0 = *(const bf16x8*)(hs + col * 120 + c * 16 + half * 8);
    bf16x8 a1 = *(const bf16x8*)(hs + (32 + col) * 120 + c * 16 + half * 8);
    acc[0] = __builtin_amdgcn_mfma_f32_32x32x16_bf16(a0, bfv, acc[0], 0, 0, 0);
    acc[1] = __builtin_amdgcn_mfma_f32_32x32x16_bf16(a1, bfv, acc[1], 0, 0, 0);
  }
}

// per-feature partial stats over this block's 64 rows -> plain stores to own slot
__device__ __forceinline__ void frag_store(const f32x16* acc, float* sl,
                                           int n, int N, int half) {
  float sm = 0.f, sq = 0.f;
#pragma unroll
  for (int m = 0; m < 2; ++m)
#pragma unroll
    for (int i = 0; i < 16; ++i) { float v = acc[m][i]; sm += v; sq += v * v; }
  sm += __shfl_xor(sm, 32);
  sq += __shfl_xor(sq, 32);
  if (half == 0) {
    agent_st(&sl[n], n < N ? sm : 0.f);
    agent_st(&sl[128 + n], n < N ? sq : 0.f);
  }
}

__device__ __forceinline__ void bn_from_cmb(const float* cmb, const float* gam,
                                            const float* bet, int n, int N,
                                            float scale, float& a, float& c) {
  a = 0.f; c = 0.f;
  if (n < N) {
    float sm = cmb[n];
    float sq = cmb[128 + n];
    float mean = sm * (1.f / 8192.f);
    float var  = fmaxf(sq * (1.f / 8192.f) - mean * mean, 0.f);
    float au = gam[n] * rsqrtf(var + 1e-6f);
    a = au * scale;
    c = (bet[n] - mean * au) * scale;
  }
}

__device__ __forceinline__ void write_h(__bf16* hs, const f32x16* acc,
                                        float a, float c, int n, int half) {
  if (n < 112) {
#pragma unroll
    for (int m = 0; m < 2; ++m)
#pragma unroll
      for (int i = 0; i < 16; ++i) {
        int row = m * 32 + (i & 3) + 8 * (i >> 2) + 4 * half;
        float v = fmaxf(acc[m][i] * a + c, 0.f);
        hs[row * 120 + n] = (__bf16)v;
      }
  }
}

__device__ __forceinline__ void write_z(float* zs, const f32x16* acc,
                                        float a, float c, int n, int half) {
  if (n < DD) {
#pragma unroll
    for (int m = 0; m < 2; ++m)
#pragma unroll
      for (int i = 0; i < 16; ++i) {
        int row = m * 32 + (i & 3) + 8 * (i >> 2) + 4 * half;
        zs[row * 104 + n] = acc[m][i] * a + c;
      }
  }
}

__global__ __launch_bounds__(NT) void bsde_kernel(Params p) {
  __shared__ float xs[ROWS * 104];
  __shared__ float zs[ROWS * 104];
  __shared__ float dws[ROWS * 104];
  __shared__ float ys[ROWS];
  __shared__ __bf16 hsb[ROWS * 120];
  __shared__ float aS[128], cS[128];
  __shared__ float cmb[256];

  const int tid  = threadIdx.x;
  const int lane = tid & 63;
  const int wv   = tid >> 6;
  const int col  = lane & 31;
  const int half = lane >> 5;
  const int n    = wv * 32 + col;
  const int b0   = blockIdx.x * ROWS;

  // ---- init persistent state ----
  {
    float z0 = p.zini[0];
    for (int i = tid; i < ROWS * 104; i += NT) { xs[i] = 1.57079632679f; zs[i] = z0; }
    if (tid < ROWS) ys[tid] = p.yini[0];
  }
  for (int idx = tid; idx < ROWS * 128; idx += NT) {
    int r = idx >> 7, d = idx & 127;
    if (d < DD) {
      const float* wr = p.W + (size_t)(b0 + r) * 6400 + d;
      dws[r * 104 + d] = wr[100] - wr[0];
    }
  }
  __syncthreads();

  for (int s = 0; s < NS; ++s) {
    // ---- phase 0: x,y update (block-local) ----
    {
      int r = tid >> 2, l4 = tid & 3;
      float yr = ys[r];
      float ssum = 0.f, zdw = 0.f;
#pragma unroll
      for (int i = 0; i < 25; ++i) {
        int d = l4 + 4 * i;
        float dw = dws[r * 104 + d];
        float xv = xs[r * 104 + d] + 0.3f * dw * yr;
        xs[r * 104 + d] = xv;
        ssum += __sinf(xv);
        zdw  += zs[r * 104 + d] * dw;
      }
      ssum += __shfl_down(ssum, 2, 4);
      ssum += __shfl_down(ssum, 1, 4);
      zdw  += __shfl_down(zdw, 2, 4);
      zdw  += __shfl_down(zdw, 1, 4);
      if (l4 == 0) {
        float ec = __expf(-0.3f * (1.f - (float)s * (1.f / 64.f)));
        float tc = 0.1f * ssum;
        float drift = -0.1f * yr + 0.045f * ec * tc * tc * tc;
        ys[r] = yr - drift * (1.f / 64.f) + zdw;
      }
    }
    __syncthreads();

    float tB[7][8];
    f32x16 acc[2];

    // ---- BN0: partial stats of [x | y] (101 features), 2 threads/feature ----
    {
      int g = s * 4 + 1, par = g & 1;
      float* sl = p.slots + (size_t)par * SLOTSZ + blockIdx.x * 256;
      int f = tid >> 1, hr = tid & 1;
      float sm = 0.f, sq = 0.f;
      if (f < 101) {
        if (f < DD) {
          for (int r = hr * 32; r < hr * 32 + 32; ++r) {
            float v = xs[r * 104 + f]; sm += v; sq += v * v;
          }
        } else {
          for (int r = hr * 32; r < hr * 32 + 32; ++r) {
            float v = ys[r]; sm += v; sq += v * v;
          }
        }
      }
      sm += __shfl_xor(sm, 1);
      sq += __shfl_xor(sq, 1);
      if (hr == 0) { agent_st(&sl[f], sm); agent_st(&sl[128 + f], sq); }
      arrive(p.flags, g);
      issueB<101, HH>(p.w0 + (size_t)s * 11110, n, half, tB);   // overlap
      wait_all(p.flags, g);
      cmb[tid] = combine_read(p.slots + (size_t)par * SLOTSZ, tid);
      __syncthreads();
      if (tid < 128) {
        float a = 0.f, c = 0.f;
        if (tid < 101) {
          float mean = cmb[tid] * (1.f / 8192.f);
          float var  = fmaxf(cmb[128 + tid] * (1.f / 8192.f) - mean * mean, 0.f);
          float au = p.g0[s * 101 + tid] * rsqrtf(var + 1e-6f);
          a = au; c = p.b0[s * 101 + tid] - mean * au;
        }
        aS[tid] = a; cS[tid] = c;
      }
      __syncthreads();
      for (int idx = tid; idx < ROWS * 128; idx += NT) {
        int r = idx >> 7, d = idx & 127;
        if (d < 112) {
          float v = (d < DD)  ? xs[r * 104 + d] * aS[d] + cS[d]
                  : (d == DD) ? ys[r] * aS[DD] + cS[DD] : 0.f;
          hsb[r * 120 + d] = (__bf16)v;
        }
      }
      __syncthreads();
    }

    // ---- L0: h @ w0 -> BN1 -> relu ----
    {
      int g = s * 4 + 2, par = g & 1;
      float* sl = p.slots + (size_t)par * SLOTSZ + blockIdx.x * 256;
      run_mfma2(hsb, tB, col, half, acc);
      frag_store(acc, sl, n, HH, half);
      arrive(p.flags, g);
      issueB<HH, HH>(p.w1 + (size_t)s * 12100, n, half, tB);
      wait_all(p.flags, g);
      cmb[tid] = combine_read(p.slots + (size_t)par * SLOTSZ, tid);
      __syncthreads();
      float a, c;
      bn_from_cmb(cmb, p.g1 + s * HH, p.b1 + s * HH, n, HH, 1.f, a, c);
      write_h(hsb, acc, a, c, n, half);
      __syncthreads();
    }
    // ---- L1: h @ w1 -> BN2 -> relu ----
    {
      int g = s * 4 + 3, par = g & 1;
      float* sl = p.slots + (size_t)par * SLOTSZ + blockIdx.x * 256;
      run_mfma2(hsb, tB, col, half, acc);
      frag_store(acc, sl, n, HH, half);
      arrive(p.flags, g);
      issueB<HH, DD>(p.w2 + (size_t)s * 11000, n, half, tB);
      wait_all(p.flags, g);
      cmb[tid] = combine_read(p.slots + (size_t)par * SLOTSZ, tid);
      __syncthreads();
      float a, c;
      bn_from_cmb(cmb, p.g2 + s * HH, p.b2 + s * HH, n, HH, 1.f, a, c);
      write_h(hsb, acc, a, c, n, half);
      __syncthreads();
    }
    // ---- L2: h @ w2 -> BN3 -> z/100  (bias2 zero & batch-constant: cancels) ----
    {
      int g = s * 4 + 4, par = g & 1;
      float* sl = p.slots + (size_t)par * SLOTSZ + blockIdx.x * 256;
      run_mfma2(hsb, tB, col, half, acc);
      frag_store(acc, sl, n, DD, half);
      arrive(p.flags, g);
      if (s + 1 < NS) {   // prefetch next step's dW under the barrier
        for (int idx = tid; idx < ROWS * 128; idx += NT) {
          int r = idx >> 7, d = idx & 127;
          if (d < DD) {
            const float* wr = p.W + (size_t)(b0 + r) * 6400 + (s + 1) * 100 + d;
            dws[r * 104 + d] = wr[100] - wr[0];
          }
        }
      }
      wait_all(p.flags, g);
      cmb[tid] = combine_read(p.slots + (size_t)par * SLOTSZ, tid);
      __syncthreads();
      float a, c;
      bn_from_cmb(cmb, p.g3 + s * DD, p.b3 + s * DD, n, DD, 0.01f, a, c);
      write_z(zs, acc, a, c, n, half);
      __syncthreads();
    }
  }

  // ---- final extra update with dW[-1] ----
  {
    int r = tid >> 2, l4 = tid & 3;
    float yr = ys[r];
    float ssum = 0.f, zdw = 0.f;
#pragma unroll
    for (int i = 0; i < 25; ++i) {
      int d = l4 + 4 * i;
      float dw = dws[r * 104 + d];
      float xv = xs[r * 104 + d] + 0.3f * dw * yr;
      xs[r * 104 + d] = xv;
      ssum += __sinf(xv);
      zdw  += zs[r * 104 + d] * dw;
    }
    ssum += __shfl_down(ssum, 2, 4);
    ssum += __shfl_down(ssum, 1, 4);
    zdw  += __shfl_down(zdw, 2, 4);
    zdw  += __shfl_down(zdw, 1, 4);
    if (l4 == 0) {
      float ec = __expf(-0.3f * (1.f - 62.f * (1.f / 64.f)));
      float tc = 0.1f * ssum;
      float drift = -0.1f * yr + 0.045f * ec * tc * tc * tc;
      ys[r] = yr - drift * (1.f / 64.f) + zdw;
    }
  }
  __syncthreads();

  // ---- outputs: x [8192,100] then y [8192,1] ----
  for (int idx = tid; idx < ROWS * 128; idx += NT) {
    int r = idx >> 7, d = idx & 127;
    if (d < DD) p.out[(size_t)(b0 + r) * 100 + d] = xs[r * 104 + d];
  }
  if (tid < ROWS) p.out[819200 + b0 + tid] = ys[tid];
}

extern "C" void kernel_launch(void* const* d_in, const int* in_sizes, int n_in,
                              void* d_out, int out_size, void* d_ws, size_t ws_size,
                              hipStream_t stream) {
  Params p;
  p.W    = (const float*)d_in[0];
  p.yini = (const float*)d_in[1];
  p.zini = (const float*)d_in[2];
  p.g0   = (const float*)d_in[3];  p.b0 = (const float*)d_in[4];
  p.g1   = (const float*)d_in[5];  p.b1 = (const float*)d_in[6];
  p.g2   = (const float*)d_in[7];  p.b2 = (const float*)d_in[8];
  p.g3   = (const float*)d_in[9];  p.b3 = (const float*)d_in[10];
  p.w0   = (const float*)d_in[11]; p.w1 = (const float*)d_in[12];
  p.w2   = (const float*)d_in[13];
  p.out   = (float*)d_out;
  p.flags = (int*)d_ws;                                  // 128 x 16 ints (8 KB)
  p.slots = (float*)((char*)d_ws + NBLK * 16 * 4);       // 2 x 128 x 256 floats

  hipMemsetAsync(d_ws, 0, NBLK * 16 * 4, stream);        // flags start at 0
  bsde_kernel<<<dim3(NBLK), dim3(NT), 0, stream>>>(p);
}

// Round 4
// 4797.942 us; speedup vs baseline: 1.9057x; 1.9057x over previous
//
#include <hip/hip_runtime.h>
#include <cstdint>
#include <cstddef>

#define NBLK 128
#define NT   256
#define ROWS 64
#define DD   100
#define HH   110
#define NS   63
#define SLOTSZ (NBLK * 256)          // floats per parity

typedef __bf16 bf16x8 __attribute__((ext_vector_type(8)));
typedef float  f32x16 __attribute__((ext_vector_type(16)));

struct Params {
  const float* W; const float* yini; const float* zini;
  const float* g0; const float* b0; const float* g1; const float* b1;
  const float* g2; const float* b2; const float* g3; const float* b3;
  const float* w0; const float* w1; const float* w2;
  float* out; float* slots; float* comb; int* fA; int* fB;
};

__device__ __forceinline__ float agent_ld(const float* p_) {
  return __hip_atomic_load(p_, __ATOMIC_RELAXED, __HIP_MEMORY_SCOPE_AGENT);
}
__device__ __forceinline__ void agent_st(float* p_, float v) {
  __hip_atomic_store(p_, v, __ATOMIC_RELAXED, __HIP_MEMORY_SCOPE_AGENT);
}

// Stage 1: arrive (partials already stored), poll all arrivals, reduce own
// 2-float column across all 128 slots, publish to comb, set flagB.
__device__ __forceinline__ void reduce_pub(int g, int* fA, int* fB,
                                           float* slotsPar, float* combPar,
                                           float* redS) {
  const int tid = threadIdx.x;
  asm volatile("s_waitcnt vmcnt(0)" ::: "memory");   // partials acked at MALL
  __syncthreads();
  if (tid == 0)
    __hip_atomic_store(&fA[blockIdx.x * 16], g, __ATOMIC_RELAXED,
                       __HIP_MEMORY_SCOPE_AGENT);
  if (tid < NBLK) {
    while (__hip_atomic_load(&fA[tid * 16], __ATOMIC_RELAXED,
                             __HIP_MEMORY_SCOPE_AGENT) < g)
      __builtin_amdgcn_s_sleep(1);
  }
  __syncthreads();
  // thread t: source block t>>1, feature-pair float (t&1) of pair 2*blockIdx.x
  float v = agent_ld(&slotsPar[(tid >> 1) * 256 + blockIdx.x * 2 + (tid & 1)]);
#pragma unroll
  for (int d = 2; d < 64; d <<= 1) v += __shfl_xor(v, d);
  int lane = tid & 63, wv = tid >> 6;
  if (lane < 2) redS[wv * 2 + lane] = v;
  __syncthreads();
  if (tid < 2) {
    float s2 = redS[tid] + redS[tid + 2] + redS[tid + 4] + redS[tid + 6];
    agent_st(&combPar[blockIdx.x * 2 + tid], s2);
  }
  asm volatile("s_waitcnt vmcnt(0)" ::: "memory");   // comb stores acked
  __syncthreads();
  if (tid == 0)
    __hip_atomic_store(&fB[blockIdx.x * 16], g, __ATOMIC_RELAXED,
                       __HIP_MEMORY_SCOPE_AGENT);
}
// Stage 2: poll all publishers, read combined 256 floats into LDS.
__device__ __forceinline__ void fetch_comb(int g, int* fB, const float* combPar,
                                           float* cmb) {
  const int tid = threadIdx.x;
  if (tid < NBLK) {
    while (__hip_atomic_load(&fB[tid * 16], __ATOMIC_RELAXED,
                             __HIP_MEMORY_SCOPE_AGENT) < g)
      __builtin_amdgcn_s_sleep(1);
  }
  __syncthreads();
  cmb[tid] = agent_ld(&combPar[tid]);
  __syncthreads();
}

// issue B-fragment global loads (w[k][n], masked to zero outside K x N)
template<int K, int N>
__device__ __forceinline__ void issueB(const float* wg, int n, int half, float (*t)[8]) {
#pragma unroll
  for (int c = 0; c < 7; ++c) {
#pragma unroll
    for (int j = 0; j < 8; ++j) {
      int k = c * 16 + half * 8 + j;
      t[c][j] = (k < K && n < N) ? wg[k * N + n] : 0.f;
    }
  }
}

// two 32-row tiles (M=64) sharing the B fragments
__device__ __forceinline__ void run_mfma2(const __bf16* hs, const float (*t)[8],
                                          int col, int half, f32x16* acc) {
  acc[0] = (f32x16)(0.f);
  acc[1] = (f32x16)(0.f);
#pragma unroll
  for (int c = 0; c < 7; ++c) {
    bf16x8 bfv;
#pragma unroll
    for (int j = 0; j < 8; ++j) bfv[j] = (__bf16)t[c][j];
    bf16x8 a0 = *(const bf16x8*)(hs + col * 120 + c * 16 + half * 8);
    bf16x8 a1 = *(const bf16x8*)(hs + (32 + col) * 120 + c * 16 + half * 8);
    acc[0] = __builtin_amdgcn_mfma_f32_32x32x16_bf16(a0, bfv, acc[0], 0, 0, 0);
    acc[1] = __builtin_amdgcn_mfma_f32_32x32x16_bf16(a1, bfv, acc[1], 0, 0, 0);
  }
}

// per-feature partial stats over this block's 64 rows -> plain stores to own slot
__device__ __forceinline__ void frag_store(const f32x16* acc, float* sl,
                                           int n, int N, int half) {
  float sm = 0.f, sq = 0.f;
#pragma unroll
  for (int m = 0; m < 2; ++m)
#pragma unroll
    for (int i = 0; i < 16; ++i) { float v = acc[m][i]; sm += v; sq += v * v; }
  sm += __shfl_xor(sm, 32);
  sq += __shfl_xor(sq, 32);
  if (half == 0) {
    agent_st(&sl[n], n < N ? sm : 0.f);
    agent_st(&sl[128 + n], n < N ? sq : 0.f);
  }
}

__device__ __forceinline__ void bn_from_cmb(const float* cmb, const float* gam,
                                            const float* bet, int n, int N,
                                            float scale, float& a, float& c) {
  a = 0.f; c = 0.f;
  if (n < N) {
    float sm = cmb[n];
    float sq = cmb[128 + n];
    float mean = sm * (1.f / 8192.f);
    float var  = fmaxf(sq * (1.f / 8192.f) - mean * mean, 0.f);
    float au = gam[n] * rsqrtf(var + 1e-6f);
    a = au * scale;
    c = (bet[n] - mean * au) * scale;
  }
}

__device__ __forceinline__ void write_h(__bf16* hs, const f32x16* acc,
                                        float a, float c, int n, int half) {
  if (n < 112) {
#pragma unroll
    for (int m = 0; m < 2; ++m)
#pragma unroll
      for (int i = 0; i < 16; ++i) {
        int row = m * 32 + (i & 3) + 8 * (i >> 2) + 4 * half;
        float v = fmaxf(acc[m][i] * a + c, 0.f);
        hs[row * 120 + n] = (__bf16)v;
      }
  }
}

__device__ __forceinline__ void write_z(float* zs, const f32x16* acc,
                                        float a, float c, int n, int half) {
  if (n < DD) {
#pragma unroll
    for (int m = 0; m < 2; ++m)
#pragma unroll
      for (int i = 0; i < 16; ++i) {
        int row = m * 32 + (i & 3) + 8 * (i >> 2) + 4 * half;
        zs[row * 104 + n] = acc[m][i] * a + c;
      }
  }
}

__global__ __launch_bounds__(NT) void bsde_kernel(Params p) {
  __shared__ float xs[ROWS * 104];
  __shared__ float zs[ROWS * 104];
  __shared__ float dws[ROWS * 104];
  __shared__ float ys[ROWS];
  __shared__ __bf16 hsb[ROWS * 120];
  __shared__ float aS[128], cS[128];
  __shared__ float cmb[256];
  __shared__ float redS[8];

  const int tid  = threadIdx.x;
  const int lane = tid & 63;
  const int wv   = tid >> 6;
  const int col  = lane & 31;
  const int half = lane >> 5;
  const int n    = wv * 32 + col;
  const int b0   = blockIdx.x * ROWS;

  // ---- init persistent state ----
  {
    float z0 = p.zini[0];
    for (int i = tid; i < ROWS * 104; i += NT) { xs[i] = 1.57079632679f; zs[i] = z0; }
    if (tid < ROWS) ys[tid] = p.yini[0];
  }
  for (int idx = tid; idx < ROWS * 128; idx += NT) {
    int r = idx >> 7, d = idx & 127;
    if (d < DD) {
      const float* wr = p.W + (size_t)(b0 + r) * 6400 + d;
      dws[r * 104 + d] = wr[100] - wr[0];
    }
  }
  __syncthreads();

  for (int s = 0; s < NS; ++s) {
    // ---- phase 0: x,y update (block-local) ----
    {
      int r = tid >> 2, l4 = tid & 3;
      float yr = ys[r];
      float ssum = 0.f, zdw = 0.f;
#pragma unroll
      for (int i = 0; i < 25; ++i) {
        int d = l4 + 4 * i;
        float dw = dws[r * 104 + d];
        float xv = xs[r * 104 + d] + 0.3f * dw * yr;
        xs[r * 104 + d] = xv;
        ssum += __sinf(xv);
        zdw  += zs[r * 104 + d] * dw;
      }
      ssum += __shfl_down(ssum, 2, 4);
      ssum += __shfl_down(ssum, 1, 4);
      zdw  += __shfl_down(zdw, 2, 4);
      zdw  += __shfl_down(zdw, 1, 4);
      if (l4 == 0) {
        float ec = __expf(-0.3f * (1.f - (float)s * (1.f / 64.f)));
        float tc = 0.1f * ssum;
        float drift = -0.1f * yr + 0.045f * ec * tc * tc * tc;
        ys[r] = yr - drift * (1.f / 64.f) + zdw;
      }
    }
    __syncthreads();

    float tB[7][8];
    f32x16 acc[2];

    // ---- BN0: partial stats of [x | y] (101 features) ----
    {
      int g = s * 4 + 1, par = g & 1;
      float* slb = p.slots + (size_t)par * SLOTSZ;
      float* sl  = slb + blockIdx.x * 256;
      float* cb  = p.comb + par * 256;
      int f = tid >> 1, hr = tid & 1;
      float sm = 0.f, sq = 0.f;
      if (f < 101) {
        if (f < DD) {
          for (int r = hr * 32; r < hr * 32 + 32; ++r) {
            float v = xs[r * 104 + f]; sm += v; sq += v * v;
          }
        } else {
          for (int r = hr * 32; r < hr * 32 + 32; ++r) {
            float v = ys[r]; sm += v; sq += v * v;
          }
        }
      }
      sm += __shfl_xor(sm, 1);
      sq += __shfl_xor(sq, 1);
      if (hr == 0) { agent_st(&sl[f], sm); agent_st(&sl[128 + f], sq); }
      reduce_pub(g, p.fA, p.fB, slb, cb, redS);
      issueB<101, HH>(p.w0 + (size_t)s * 11110, n, half, tB);   // overlap pollB
      fetch_comb(g, p.fB, cb, cmb);
      if (tid < 128) {
        float a = 0.f, c = 0.f;
        if (tid < 101) {
          float mean = cmb[tid] * (1.f / 8192.f);
          float var  = fmaxf(cmb[128 + tid] * (1.f / 8192.f) - mean * mean, 0.f);
          float au = p.g0[s * 101 + tid] * rsqrtf(var + 1e-6f);
          a = au; c = p.b0[s * 101 + tid] - mean * au;
        }
        aS[tid] = a; cS[tid] = c;
      }
      __syncthreads();
      for (int idx = tid; idx < ROWS * 128; idx += NT) {
        int r = idx >> 7, d = idx & 127;
        if (d < 112) {
          float v = (d < DD)  ? xs[r * 104 + d] * aS[d] + cS[d]
                  : (d == DD) ? ys[r] * aS[DD] + cS[DD] : 0.f;
          hsb[r * 120 + d] = (__bf16)v;
        }
      }
      __syncthreads();
    }

    // ---- L0: h @ w0 -> BN1 -> relu ----
    {
      int g = s * 4 + 2, par = g & 1;
      float* slb = p.slots + (size_t)par * SLOTSZ;
      float* cb  = p.comb + par * 256;
      run_mfma2(hsb, tB, col, half, acc);
      frag_store(acc, slb + blockIdx.x * 256, n, HH, half);
      reduce_pub(g, p.fA, p.fB, slb, cb, redS);
      issueB<HH, HH>(p.w1 + (size_t)s * 12100, n, half, tB);
      fetch_comb(g, p.fB, cb, cmb);
      float a, c;
      bn_from_cmb(cmb, p.g1 + s * HH, p.b1 + s * HH, n, HH, 1.f, a, c);
      write_h(hsb, acc, a, c, n, half);
      __syncthreads();
    }
    // ---- L1: h @ w1 -> BN2 -> relu ----
    {
      int g = s * 4 + 3, par = g & 1;
      float* slb = p.slots + (size_t)par * SLOTSZ;
      float* cb  = p.comb + par * 256;
      run_mfma2(hsb, tB, col, half, acc);
      frag_store(acc, slb + blockIdx.x * 256, n, HH, half);
      reduce_pub(g, p.fA, p.fB, slb, cb, redS);
      issueB<HH, DD>(p.w2 + (size_t)s * 11000, n, half, tB);
      fetch_comb(g, p.fB, cb, cmb);
      float a, c;
      bn_from_cmb(cmb, p.g2 + s * HH, p.b2 + s * HH, n, HH, 1.f, a, c);
      write_h(hsb, acc, a, c, n, half);
      __syncthreads();
    }
    // ---- L2: h @ w2 -> BN3 -> z/100 (bias2 zero & batch-constant: cancels) ----
    {
      int g = s * 4 + 4, par = g & 1;
      float* slb = p.slots + (size_t)par * SLOTSZ;
      float* cb  = p.comb + par * 256;
      run_mfma2(hsb, tB, col, half, acc);
      frag_store(acc, slb + blockIdx.x * 256, n, DD, half);
      reduce_pub(g, p.fA, p.fB, slb, cb, redS);
      if (s + 1 < NS) {   // prefetch next step's dW during pollB
        for (int idx = tid; idx < ROWS * 128; idx += NT) {
          int r = idx >> 7, d = idx & 127;
          if (d < DD) {
            const float* wr = p.W + (size_t)(b0 + r) * 6400 + (s + 1) * 100 + d;
            dws[r * 104 + d] = wr[100] - wr[0];
          }
        }
      }
      fetch_comb(g, p.fB, cb, cmb);
      float a, c;
      bn_from_cmb(cmb, p.g3 + s * DD, p.b3 + s * DD, n, DD, 0.01f, a, c);
      write_z(zs, acc, a, c, n, half);
      __syncthreads();
    }
  }

  // ---- final extra update with dW[-1] ----
  {
    int r = tid >> 2, l4 = tid & 3;
    float yr = ys[r];
    float ssum = 0.f, zdw = 0.f;
#pragma unroll
    for (int i = 0; i < 25; ++i) {
      int d = l4 + 4 * i;
      float dw = dws[r * 104 + d];
      float xv = xs[r * 104 + d] + 0.3f * dw * yr;
      xs[r * 104 + d] = xv;
      ssum += __sinf(xv);
      zdw  += zs[r * 104 + d] * dw;
    }
    ssum += __shfl_down(ssum, 2, 4);
    ssum += __shfl_down(ssum, 1, 4);
    zdw  += __shfl_down(zdw, 2, 4);
    zdw  += __shfl_down(zdw, 1, 4);
    if (l4 == 0) {
      float ec = __expf(-0.3f * (1.f - 62.f * (1.f / 64.f)));
      float tc = 0.1f * ssum;
      float drift = -0.1f * yr + 0.045f * ec * tc * tc * tc;
      ys[r] = yr - drift * (1.f / 64.f) + zdw;
    }
  }
  __syncthreads();

  // ---- outputs: x [8192,100] then y [8192,1] ----
  for (int idx = tid; idx < ROWS * 128; idx += NT) {
    int r = idx >> 7, d = idx & 127;
    if (d < DD) p.out[(size_t)(b0 + r) * 100 + d] = xs[r * 104 + d];
  }
  if (tid < ROWS) p.out[819200 + b0 + tid] = ys[tid];
}

extern "C" void kernel_launch(void* const* d_in, const int* in_sizes, int n_in,
                              void* d_out, int out_size, void* d_ws, size_t ws_size,
                              hipStream_t stream) {
  Params p;
  p.W    = (const float*)d_in[0];
  p.yini = (const float*)d_in[1];
  p.zini = (const float*)d_in[2];
  p.g0   = (const float*)d_in[3];  p.b0 = (const float*)d_in[4];
  p.g1   = (const float*)d_in[5];  p.b1 = (const float*)d_in[6];
  p.g2   = (const float*)d_in[7];  p.b2 = (const float*)d_in[8];
  p.g3   = (const float*)d_in[9];  p.b3 = (const float*)d_in[10];
  p.w0   = (const float*)d_in[11]; p.w1 = (const float*)d_in[12];
  p.w2   = (const float*)d_in[13];
  p.out   = (float*)d_out;
  p.fA    = (int*)d_ws;                                   // 128 x 16 ints
  p.fB    = (int*)((char*)d_ws + 8192);                   // 128 x 16 ints
  p.slots = (float*)((char*)d_ws + 16384);                // 2 x 128 x 256 floats
  p.comb  = (float*)((char*)d_ws + 16384 + 262144);       // 2 x 256 floats

  hipMemsetAsync(d_ws, 0, 16384, stream);                 // flags start at 0
  bsde_kernel<<<dim3(NBLK), dim3(NT), 0, stream>>>(p);
}

// Round 5
// 4398.154 us; speedup vs baseline: 2.0790x; 1.0909x over previous
//
#include <hip/hip_runtime.h>
#include <cstdint>
#include <cstddef>

#define NBLK 128
#define NT   256
#define ROWS 64
#define DD   100
#define HH   110
#define NS   63

typedef __bf16 bf16x8 __attribute__((ext_vector_type(8)));
typedef float  f32x16 __attribute__((ext_vector_type(16)));

struct Params {
  const float* W; const float* yini; const float* zini;
  const float* g0; const float* b0; const float* g1; const float* b1;
  const float* g2; const float* b2; const float* g3; const float* b3;
  const float* w0; const float* w1; const float* w2;
  float* out;
  float* slotX;   // [par][xid][feat(256)][member(128)]  (XCD-local, sc0/L2)
  float* xslotT;  // [par][feat(256)][xid(8)]            (MALL, agent ops only)
  float* finT;    // [par][xid][feat(256)]               (XCD-local, sc0/L2)
  int* fxloc;     // [xid][member] stride 16 ints        (XCD-local)
  int* gA;        // [xid] stride 16                     (MALL)
  int* gBloc;     // [xid] stride 16                     (XCD-local)
  int* xcnt;      // [xid] stride 16                     (MALL, registration)
  int* initcnt;   // 1                                   (MALL, registration)
};

// ---- access helpers ----
// volatile -> sc0: bypass L1, coherent at the XCD's L2 (intra-XCD comms)
__device__ __forceinline__ float vld(const float* p_) { return *(const volatile float*)p_; }
__device__ __forceinline__ void  vst(float* p_, float v) { *(volatile float*)p_ = v; }
__device__ __forceinline__ int   vldi(const int* p_) { return *(const volatile int*)p_; }
__device__ __forceinline__ void  vsti(int* p_, int v) { *(volatile int*)p_ = v; }
// agent-scope relaxed atomics -> bypass L1+L2, coherent at MALL (cross-XCD)
__device__ __forceinline__ float agent_ld(const float* p_) {
  return __hip_atomic_load(p_, __ATOMIC_RELAXED, __HIP_MEMORY_SCOPE_AGENT);
}
__device__ __forceinline__ void agent_st(float* p_, float v) {
  __hip_atomic_store(p_, v, __ATOMIC_RELAXED, __HIP_MEMORY_SCOPE_AGENT);
}
__device__ __forceinline__ int agent_ldi(const int* p_) {
  return __hip_atomic_load(p_, __ATOMIC_RELAXED, __HIP_MEMORY_SCOPE_AGENT);
}
__device__ __forceinline__ void agent_sti(int* p_, int v) {
  __hip_atomic_store(p_, v, __ATOMIC_RELAXED, __HIP_MEMORY_SCOPE_AGENT);
}

// ---- hierarchical sync, part A: member arrival + leader duty ----
__device__ __forceinline__ void sync_arrive(int g, int xid, int m, int cntx,
                                            int cntx8, bool lead, const int* cntS,
                                            const Params& p) {
  const int tid = threadIdx.x;
  const int par = g & 1;
  asm volatile("s_waitcnt vmcnt(0)" ::: "memory");   // partials in L2
  __syncthreads();
  if (tid == 0) vsti(&p.fxloc[(xid * 128 + m) * 16], g);
  if (lead) {
    if (tid < cntx)
      while (vldi(&p.fxloc[(xid * 128 + tid) * 16]) < g) __builtin_amdgcn_s_sleep(1);
    __syncthreads();
    // gather members' partials from XCD L2 (8-wide pipelined volatile loads)
    float* sx = p.slotX + (size_t)((par * 8 + xid) * 256 + tid) * 128;
    float s = 0.f;
    for (int mm = 0; mm < cntx8; mm += 8) {
      float t0 = vld(sx + mm + 0), t1 = vld(sx + mm + 1);
      float t2 = vld(sx + mm + 2), t3 = vld(sx + mm + 3);
      float t4 = vld(sx + mm + 4), t5 = vld(sx + mm + 5);
      float t6 = vld(sx + mm + 6), t7 = vld(sx + mm + 7);
      s += ((t0 + t1) + (t2 + t3)) + ((t4 + t5) + (t6 + t7));
    }
    agent_st(&p.xslotT[(par * 256 + tid) * 8 + xid], s);
    asm volatile("s_waitcnt vmcnt(0)" ::: "memory");  // xslot at MALL
    __syncthreads();
    if (tid == 0) agent_sti(&p.gA[xid * 16], g);
    // global rendezvous: 8 leaders only
    if (tid < 8 && cntS[tid] > 0)
      while (agent_ldi(&p.gA[tid * 16]) < g) __builtin_amdgcn_s_sleep(1);
    __syncthreads();
    float tot = 0.f;
#pragma unroll
    for (int x = 0; x < 8; ++x) {
      float v = agent_ld(&p.xslotT[(par * 256 + tid) * 8 + x]);
      tot += (cntS[x] > 0) ? v : 0.f;
    }
    vst(&p.finT[(par * 8 + xid) * 256 + tid], tot);   // rebroadcast via L2
    asm volatile("s_waitcnt vmcnt(0)" ::: "memory");
    __syncthreads();
    if (tid == 0) vsti(&p.gBloc[xid * 16], g);
  }
}
// ---- part B: wait for own XCD's broadcast, fetch combined stats ----
__device__ __forceinline__ void sync_fetch(int g, int xid, float* cmb,
                                           const Params& p) {
  const int tid = threadIdx.x;
  const int par = g & 1;
  if (tid == 0)
    while (vldi(&p.gBloc[xid * 16]) < g) __builtin_amdgcn_s_sleep(1);
  __syncthreads();
  cmb[tid] = vld(&p.finT[(par * 8 + xid) * 256 + tid]);
  __syncthreads();
}

// issue B-fragment global loads (w[k][n], masked to zero outside K x N)
template<int K, int N>
__device__ __forceinline__ void issueB(const float* wg, int n, int half, float (*t)[8]) {
#pragma unroll
  for (int c = 0; c < 7; ++c) {
#pragma unroll
    for (int j = 0; j < 8; ++j) {
      int k = c * 16 + half * 8 + j;
      t[c][j] = (k < K && n < N) ? wg[k * N + n] : 0.f;
    }
  }
}

// two 32-row tiles (M=64) sharing the B fragments
__device__ __forceinline__ void run_mfma2(const __bf16* hs, const float (*t)[8],
                                          int col, int half, f32x16* acc) {
  acc[0] = (f32x16)(0.f);
  acc[1] = (f32x16)(0.f);
#pragma unroll
  for (int c = 0; c < 7; ++c) {
    bf16x8 bfv;
#pragma unroll
    for (int j = 0; j < 8; ++j) bfv[j] = (__bf16)t[c][j];
    bf16x8 a0 = *(const bf16x8*)(hs + col * 120 + c * 16 + half * 8);
    bf16x8 a1 = *(const bf16x8*)(hs + (32 + col) * 120 + c * 16 + half * 8);
    acc[0] = __builtin_amdgcn_mfma_f32_32x32x16_bf16(a0, bfv, acc[0], 0, 0, 0);
    acc[1] = __builtin_amdgcn_mfma_f32_32x32x16_bf16(a1, bfv, acc[1], 0, 0, 0);
  }
}

// per-feature partial stats over this block's 64 rows -> volatile stores (L2)
__device__ __forceinline__ void frag_store(const f32x16* acc, float* slbase,
                                           int m, int n, int N, int half) {
  float sm = 0.f, sq = 0.f;
#pragma unroll
  for (int mm = 0; mm < 2; ++mm)
#pragma unroll
    for (int i = 0; i < 16; ++i) { float v = acc[mm][i]; sm += v; sq += v * v; }
  sm += __shfl_xor(sm, 32);
  sq += __shfl_xor(sq, 32);
  if (half == 0) {
    vst(slbase + (size_t)n * 128 + m, n < N ? sm : 0.f);
    vst(slbase + (size_t)(128 + n) * 128 + m, n < N ? sq : 0.f);
  }
}

__device__ __forceinline__ void bn_from_cmb(const float* cmb, const float* gam,
                                            const float* bet, int n, int N,
                                            float scale, float& a, float& c) {
  a = 0.f; c = 0.f;
  if (n < N) {
    float sm = cmb[n];
    float sq = cmb[128 + n];
    float mean = sm * (1.f / 8192.f);
    float var  = fmaxf(sq * (1.f / 8192.f) - mean * mean, 0.f);
    float au = gam[n] * rsqrtf(var + 1e-6f);
    a = au * scale;
    c = (bet[n] - mean * au) * scale;
  }
}

__device__ __forceinline__ void write_h(__bf16* hs, const f32x16* acc,
                                        float a, float c, int n, int half) {
  if (n < 112) {
#pragma unroll
    for (int m = 0; m < 2; ++m)
#pragma unroll
      for (int i = 0; i < 16; ++i) {
        int row = m * 32 + (i & 3) + 8 * (i >> 2) + 4 * half;
        float v = fmaxf(acc[m][i] * a + c, 0.f);
        hs[row * 120 + n] = (__bf16)v;
      }
  }
}

__device__ __forceinline__ void write_z(float* zs, const f32x16* acc,
                                        float a, float c, int n, int half) {
  if (n < DD) {
#pragma unroll
    for (int m = 0; m < 2; ++m)
#pragma unroll
      for (int i = 0; i < 16; ++i) {
        int row = m * 32 + (i & 3) + 8 * (i >> 2) + 4 * half;
        zs[row * 104 + n] = acc[m][i] * a + c;
      }
  }
}

__global__ __launch_bounds__(NT) void bsde_kernel(Params p) {
  __shared__ float xs[ROWS * 104];
  __shared__ float zs[ROWS * 104];
  __shared__ float dws[ROWS * 104];
  __shared__ float ys[ROWS];
  __shared__ __bf16 hsb[ROWS * 120];
  __shared__ float aS[128], cS[128];
  __shared__ float cmb[256];
  __shared__ int xidS, mS, cntSs[8];

  const int tid  = threadIdx.x;
  const int lane = tid & 63;
  const int wv   = tid >> 6;
  const int col  = lane & 31;
  const int half = lane >> 5;
  const int n    = wv * 32 + col;
  const int b0   = blockIdx.x * ROWS;

  // ---- registration: real XCD id + member index + grid rendezvous ----
  if (tid == 0) {
    int xid;
    asm volatile("s_getreg_b32 %0, hwreg(20, 0, 32)" : "=s"(xid));  // HW_REG_XCC_ID
    xid &= 7;
    int mm = __hip_atomic_fetch_add(&p.xcnt[xid * 16], 1, __ATOMIC_RELAXED,
                                    __HIP_MEMORY_SCOPE_AGENT);
    __hip_atomic_fetch_add(p.initcnt, 1, __ATOMIC_RELAXED, __HIP_MEMORY_SCOPE_AGENT);
    while (__hip_atomic_load(p.initcnt, __ATOMIC_RELAXED,
                             __HIP_MEMORY_SCOPE_AGENT) < NBLK)
      __builtin_amdgcn_s_sleep(8);
    xidS = xid; mS = mm;
  }
  __syncthreads();
  const int xid = xidS, m = mS;
  if (tid < 8) cntSs[tid] = agent_ldi(&p.xcnt[tid * 16]);
  __syncthreads();
  const bool lead  = (m == 0);
  const int  cntx  = cntSs[xid];
  const int  cntx8 = (cntx + 7) & ~7;
  float* const slbase = p.slotX;  // indexed per-parity below

  // leader zero-pads member slots [cntx, cntx8) for both parities
  if (lead) {
    int pad = cntx8 - cntx;
    for (int idx = tid; idx < 256 * pad * 2; idx += NT) {
      int f = idx & 255, rem = idx >> 8;          // rem in [0, pad*2)
      int mm2 = cntx + (rem % pad), par2 = rem / pad;
      vst(&p.slotX[(size_t)((par2 * 8 + xid) * 256 + f) * 128 + mm2], 0.f);
    }
  }

  // ---- init persistent state ----
  {
    float z0 = p.zini[0];
    for (int i = tid; i < ROWS * 104; i += NT) { xs[i] = 1.57079632679f; zs[i] = z0; }
    if (tid < ROWS) ys[tid] = p.yini[0];
  }
  for (int idx = tid; idx < ROWS * 128; idx += NT) {
    int r = idx >> 7, d = idx & 127;
    if (d < DD) {
      const float* wr = p.W + (size_t)(b0 + r) * 6400 + d;
      dws[r * 104 + d] = wr[100] - wr[0];
    }
  }
  __syncthreads();

  for (int s = 0; s < NS; ++s) {
    // ---- phase 0: x,y update (block-local) ----
    {
      int r = tid >> 2, l4 = tid & 3;
      float yr = ys[r];
      float ssum = 0.f, zdw = 0.f;
#pragma unroll
      for (int i = 0; i < 25; ++i) {
        int d = l4 + 4 * i;
        float dw = dws[r * 104 + d];
        float xv = xs[r * 104 + d] + 0.3f * dw * yr;
        xs[r * 104 + d] = xv;
        ssum += __sinf(xv);
        zdw  += zs[r * 104 + d] * dw;
      }
      ssum += __shfl_down(ssum, 2, 4);
      ssum += __shfl_down(ssum, 1, 4);
      zdw  += __shfl_down(zdw, 2, 4);
      zdw  += __shfl_down(zdw, 1, 4);
      if (l4 == 0) {
        float ec = __expf(-0.3f * (1.f - (float)s * (1.f / 64.f)));
        float tc = 0.1f * ssum;
        float drift = -0.1f * yr + 0.045f * ec * tc * tc * tc;
        ys[r] = yr - drift * (1.f / 64.f) + zdw;
      }
    }
    __syncthreads();

    float tB[7][8];
    f32x16 acc[2];

    // ---- BN0: partial stats of [x | y] (101 features) ----
    {
      int g = s * 4 + 1, par = g & 1;
      float* sl = slbase + (size_t)((par * 8 + xid) * 256) * 128;
      int f = tid >> 1, hr = tid & 1;
      float sm = 0.f, sq = 0.f;
      if (f < 101) {
        if (f < DD) {
          for (int r = hr * 32; r < hr * 32 + 32; ++r) {
            float v = xs[r * 104 + f]; sm += v; sq += v * v;
          }
        } else {
          for (int r = hr * 32; r < hr * 32 + 32; ++r) {
            float v = ys[r]; sm += v; sq += v * v;
          }
        }
      }
      sm += __shfl_xor(sm, 1);
      sq += __shfl_xor(sq, 1);
      if (hr == 0) {
        vst(sl + (size_t)f * 128 + m, sm);
        vst(sl + (size_t)(128 + f) * 128 + m, sq);
      }
      sync_arrive(g, xid, m, cntx, cntx8, lead, cntSs, p);
      issueB<101, HH>(p.w0 + (size_t)s * 11110, n, half, tB);   // overlap wait
      sync_fetch(g, xid, cmb, p);
      if (tid < 128) {
        float a = 0.f, c = 0.f;
        if (tid < 101) {
          float mean = cmb[tid] * (1.f / 8192.f);
          float var  = fmaxf(cmb[128 + tid] * (1.f / 8192.f) - mean * mean, 0.f);
          float au = p.g0[s * 101 + tid] * rsqrtf(var + 1e-6f);
          a = au; c = p.b0[s * 101 + tid] - mean * au;
        }
        aS[tid] = a; cS[tid] = c;
      }
      __syncthreads();
      for (int idx = tid; idx < ROWS * 128; idx += NT) {
        int r = idx >> 7, d = idx & 127;
        if (d < 112) {
          float v = (d < DD)  ? xs[r * 104 + d] * aS[d] + cS[d]
                  : (d == DD) ? ys[r] * aS[DD] + cS[DD] : 0.f;
          hsb[r * 120 + d] = (__bf16)v;
        }
      }
      __syncthreads();
    }

    // ---- L0: h @ w0 -> BN1 -> relu ----
    {
      int g = s * 4 + 2, par = g & 1;
      float* sl = slbase + (size_t)((par * 8 + xid) * 256) * 128;
      run_mfma2(hsb, tB, col, half, acc);
      frag_store(acc, sl, m, n, HH, half);
      sync_arrive(g, xid, m, cntx, cntx8, lead, cntSs, p);
      issueB<HH, HH>(p.w1 + (size_t)s * 12100, n, half, tB);
      sync_fetch(g, xid, cmb, p);
      float a, c;
      bn_from_cmb(cmb, p.g1 + s * HH, p.b1 + s * HH, n, HH, 1.f, a, c);
      write_h(hsb, acc, a, c, n, half);
      __syncthreads();
    }
    // ---- L1: h @ w1 -> BN2 -> relu ----
    {
      int g = s * 4 + 3, par = g & 1;
      float* sl = slbase + (size_t)((par * 8 + xid) * 256) * 128;
      run_mfma2(hsb, tB, col, half, acc);
      frag_store(acc, sl, m, n, HH, half);
      sync_arrive(g, xid, m, cntx, cntx8, lead, cntSs, p);
      issueB<HH, DD>(p.w2 + (size_t)s * 11000, n, half, tB);
      sync_fetch(g, xid, cmb, p);
      float a, c;
      bn_from_cmb(cmb, p.g2 + s * HH, p.b2 + s * HH, n, HH, 1.f, a, c);
      write_h(hsb, acc, a, c, n, half);
      __syncthreads();
    }
    // ---- L2: h @ w2 -> BN3 -> z/100 (bias2 zero & batch-constant: cancels) ----
    {
      int g = s * 4 + 4, par = g & 1;
      float* sl = slbase + (size_t)((par * 8 + xid) * 256) * 128;
      run_mfma2(hsb, tB, col, half, acc);
      frag_store(acc, sl, m, n, DD, half);
      sync_arrive(g, xid, m, cntx, cntx8, lead, cntSs, p);
      if (s + 1 < NS) {   // prefetch next step's dW while waiting
        for (int idx = tid; idx < ROWS * 128; idx += NT) {
          int r = idx >> 7, d = idx & 127;
          if (d < DD) {
            const float* wr = p.W + (size_t)(b0 + r) * 6400 + (s + 1) * 100 + d;
            dws[r * 104 + d] = wr[100] - wr[0];
          }
        }
      }
      sync_fetch(g, xid, cmb, p);
      float a, c;
      bn_from_cmb(cmb, p.g3 + s * DD, p.b3 + s * DD, n, DD, 0.01f, a, c);
      write_z(zs, acc, a, c, n, half);
      __syncthreads();
    }
  }

  // ---- final extra update with dW[-1] ----
  {
    int r = tid >> 2, l4 = tid & 3;
    float yr = ys[r];
    float ssum = 0.f, zdw = 0.f;
#pragma unroll
    for (int i = 0; i < 25; ++i) {
      int d = l4 + 4 * i;
      float dw = dws[r * 104 + d];
      float xv = xs[r * 104 + d] + 0.3f * dw * yr;
      xs[r * 104 + d] = xv;
      ssum += __sinf(xv);
      zdw  += zs[r * 104 + d] * dw;
    }
    ssum += __shfl_down(ssum, 2, 4);
    ssum += __shfl_down(ssum, 1, 4);
    zdw  += __shfl_down(zdw, 2, 4);
    zdw  += __shfl_down(zdw, 1, 4);
    if (l4 == 0) {
      float ec = __expf(-0.3f * (1.f - 62.f * (1.f / 64.f)));
      float tc = 0.1f * ssum;
      float drift = -0.1f * yr + 0.045f * ec * tc * tc * tc;
      ys[r] = yr - drift * (1.f / 64.f) + zdw;
    }
  }
  __syncthreads();

  // ---- outputs: x [8192,100] then y [8192,1] ----
  for (int idx = tid; idx < ROWS * 128; idx += NT) {
    int r = idx >> 7, d = idx & 127;
    if (d < DD) p.out[(size_t)(b0 + r) * 100 + d] = xs[r * 104 + d];
  }
  if (tid < ROWS) p.out[819200 + b0 + tid] = ys[tid];
}

extern "C" void kernel_launch(void* const* d_in, const int* in_sizes, int n_in,
                              void* d_out, int out_size, void* d_ws, size_t ws_size,
                              hipStream_t stream) {
  Params p;
  p.W    = (const float*)d_in[0];
  p.yini = (const float*)d_in[1];
  p.zini = (const float*)d_in[2];
  p.g0   = (const float*)d_in[3];  p.b0 = (const float*)d_in[4];
  p.g1   = (const float*)d_in[5];  p.b1 = (const float*)d_in[6];
  p.g2   = (const float*)d_in[7];  p.b2 = (const float*)d_in[8];
  p.g3   = (const float*)d_in[9];  p.b3 = (const float*)d_in[10];
  p.w0   = (const float*)d_in[11]; p.w1 = (const float*)d_in[12];
  p.w2   = (const float*)d_in[13];
  p.out  = (float*)d_out;

  char* ws = (char*)d_ws;
  p.fxloc   = (int*)(ws + 0);             // 8*128*16 ints = 64 KB
  p.gA      = (int*)(ws + 65536);         // 512 B
  p.gBloc   = (int*)(ws + 66048);         // 512 B
  p.xcnt    = (int*)(ws + 66560);         // 512 B
  p.initcnt = (int*)(ws + 67072);         // 64 B
  p.slotX   = (float*)(ws + 131072);      // 2*8*256*128 floats = 2 MB
  p.xslotT  = (float*)(ws + 131072 + 2097152);            // 16 KB
  p.finT    = (float*)(ws + 131072 + 2097152 + 16384);    // 16 KB

  hipMemsetAsync(d_ws, 0, 67584, stream);  // flags/counters start at 0
  bsde_kernel<<<dim3(NBLK), dim3(NT), 0, stream>>>(p);
}